// Round 7
// baseline (146.920 us; speedup 1.0000x reference)
//
#include <hip/hip_runtime.h>
#include <math.h>

#define H 256
#define HH 128
#define B_GRAPHS 512

typedef __attribute__((ext_vector_type(8))) _Float16 half8;
typedef __attribute__((ext_vector_type(16))) float f32x16;

// ---------------- K0: pre-split W1 into 2 fp16 planes (residual x4096), fragment-major ----
// plane p: base = ((ks*2+g)*128 + col)*8 + e   where k = ks*16 + g*8 + e
__global__ void k_prep_w1(const float* __restrict__ W1, ushort* __restrict__ W1f) {
  const int idx = blockIdx.x * 256 + threadIdx.x;  // 32768 = 256*128
  const int k = idx >> 7, c = idx & 127;
  const float v = W1[idx];  // W1 is [256][128] row-major
  const _Float16 h1 = (_Float16)v;
  const float r = (v - (float)h1) * 4096.f;
  const _Float16 h2 = (_Float16)r;
  const int base = (((k >> 4) * 2 + ((k >> 3) & 1)) * 128 + c) * 8 + (k & 7);
  W1f[base] = __builtin_bit_cast(ushort, h1);
  W1f[32768 + base] = __builtin_bit_cast(ushort, h2);
}

// ---------------- K1: segment bounds (batch is sorted) ----------------
__global__ void k_seg_bounds(const int* __restrict__ batch, int* __restrict__ seg_start,
                             int N, int B) {
  int b = blockIdx.x * blockDim.x + threadIdx.x;
  if (b > B) return;
  int lo = 0, hi = N;
  while (lo < hi) {
    int mid = (lo + hi) >> 1;
    if (batch[mid] < b) lo = mid + 1; else hi = mid;
  }
  seg_start[b] = lo;
}

// ---------------- K2: score MLP, 128x128 tile, BK=64, 4 iters, fp16 2-split ----------------
__device__ __forceinline__ void split8(const float4 v0, const float4 v1, half8& m, half8& r) {
  const float vals[8] = {v0.x, v0.y, v0.z, v0.w, v1.x, v1.y, v1.z, v1.w};
#pragma unroll
  for (int e = 0; e < 8; ++e) {
    const _Float16 h = (_Float16)vals[e];
    m[e] = h;
    r[e] = (_Float16)((vals[e] - (float)h) * 4096.f);
  }
}

__global__ __launch_bounds__(256, 2) void k_score_mfma(
    const float* __restrict__ x, const ushort* __restrict__ W1f,
    const float* __restrict__ b1, const float* __restrict__ W2,
    const float* __restrict__ b2, float* __restrict__ s_out) {
  // A: 2 planes x [128][76] fp16 (38912 ush B*2=38.9KB) ; B: 2 planes x 8192 fp16 (32KB)
  __shared__ ushort smem[35840];  // 71680 B total
  ushort* ash = smem;             // plane stride 9728
  ushort* bsh = smem + 19456;     // plane stride 8192
  const int t = threadIdx.x;
  const int lane = t & 63;
  const int w = t >> 6;
  const int wr = w >> 1, wc = w & 1;
  const int nl = lane & 31, g = lane >> 5;
  const int node0 = blockIdx.x * 128;

  const f32x16 zero = (f32x16)0.0f;
  f32x16 acc1[2][2], acc2[2][2];
#pragma unroll
  for (int i = 0; i < 2; ++i)
#pragma unroll
    for (int j = 0; j < 2; ++j) { acc1[i][j] = zero; acc2[i][j] = zero; }

  // A staging: rows q*32 + (t>>3), 32B per lane (2 float4) at col (t&7)*8
  const int arow = t >> 3;          // 0..31
  const int acol = (t & 7) * 8;     // 0..56
  const float* agsrc = x + (size_t)(node0 + arow) * H + acol;
  // B staging: thread t copies 64 contiguous ushorts of plane (t>>7)
  const int bp = t >> 7;
  const int boff = (t & 127) * 64;
  const ushort* bgsrc = W1f + bp * 32768 + boff;

  float4 gxa[4][2];
  uint4 gxb[8];
  // prologue: load iter 0
#pragma unroll
  for (int q = 0; q < 4; ++q) {
    gxa[q][0] = *(const float4*)(agsrc + q * 32 * H);
    gxa[q][1] = *(const float4*)(agsrc + q * 32 * H + 4);
  }
#pragma unroll
  for (int j = 0; j < 8; ++j) gxb[j] = *(const uint4*)(bgsrc + j * 8);

#pragma unroll
  for (int it = 0; it < 4; ++it) {
    // ---- stage current iter into LDS ----
#pragma unroll
    for (int q = 0; q < 4; ++q) {
      half8 m8, r8;
      split8(gxa[q][0], gxa[q][1], m8, r8);
      const int R = q * 32 + arow;
      *(uint4*)&ash[0 * 9728 + R * 76 + acol] = __builtin_bit_cast(uint4, m8);
      *(uint4*)&ash[1 * 9728 + R * 76 + acol] = __builtin_bit_cast(uint4, r8);
    }
#pragma unroll
    for (int j = 0; j < 8; ++j)
      *(uint4*)&bsh[bp * 8192 + boff + j * 8] = gxb[j];
    __syncthreads();
    // ---- prefetch next iter into regs (hidden under compute) ----
    if (it < 3) {
      const int kc = (it + 1) * 64;
#pragma unroll
      for (int q = 0; q < 4; ++q) {
        gxa[q][0] = *(const float4*)(agsrc + q * 32 * H + kc);
        gxa[q][1] = *(const float4*)(agsrc + q * 32 * H + kc + 4);
      }
#pragma unroll
      for (int j = 0; j < 8; ++j)
        gxb[j] = *(const uint4*)(bgsrc + (it + 1) * 8192 + j * 8);
    }
    // ---- compute: 4 substeps x 12 MFMA ----
#pragma unroll
    for (int sub = 0; sub < 4; ++sub) {
      half8 a0[2], a1[2], b0[2], b1[2];
#pragma unroll
      for (int i = 0; i < 2; ++i) {
        const int R = wr * 64 + i * 32 + nl;
        a0[i] = *(const half8*)&ash[0 * 9728 + R * 76 + sub * 16 + g * 8];
        a1[i] = *(const half8*)&ash[1 * 9728 + R * 76 + sub * 16 + g * 8];
      }
#pragma unroll
      for (int j = 0; j < 2; ++j) {
        const int col = wc * 64 + j * 32 + nl;
        b0[j] = *(const half8*)&bsh[0 * 8192 + ((sub * 2 + g) * 128 + col) * 8];
        b1[j] = *(const half8*)&bsh[1 * 8192 + ((sub * 2 + g) * 128 + col) * 8];
      }
#pragma unroll
      for (int i = 0; i < 2; ++i)
#pragma unroll
        for (int j = 0; j < 2; ++j) {
          acc1[i][j] = __builtin_amdgcn_mfma_f32_32x32x16_f16(a0[i], b0[j], acc1[i][j], 0, 0, 0);
          acc2[i][j] = __builtin_amdgcn_mfma_f32_32x32x16_f16(a0[i], b1[j], acc2[i][j], 0, 0, 0);
          acc2[i][j] = __builtin_amdgcn_mfma_f32_32x32x16_f16(a1[i], b0[j], acc2[i][j], 0, 0, 0);
        }
    }
    __syncthreads();
  }

  // ---- epilogue: layer 2 in fp32 (proven C/D mapping) ----
  float* part = (float*)smem;  // [128][64]
  const float inv4096 = 2.44140625e-4f;
  const int col0 = wc * 64 + nl;
  const float b1v0 = b1[col0], b1v1 = b1[col0 + 32];
  const float w2v0 = W2[col0], w2v1 = W2[col0 + 32];
#pragma unroll
  for (int i = 0; i < 2; ++i) {
#pragma unroll
    for (int r = 0; r < 16; ++r) {
      const int nodeL = wr * 64 + i * 32 + (r & 3) + 8 * (r >> 2) + 4 * g;
      const float h0 = acc1[i][0][r] + acc2[i][0][r] * inv4096 + b1v0;
      const float h1 = acc1[i][1][r] + acc2[i][1][r] * inv4096 + b1v1;
      const float p = fmaxf(h0, 0.f) * w2v0 + fmaxf(h1, 0.f) * w2v1;
      part[nodeL * 64 + wc * 32 + nl] = p;
    }
  }
  __syncthreads();
  if (t < 128) {
    float sv = b2[0];
#pragma unroll 8
    for (int cc = 0; cc < 64; ++cc) {
      sv += part[t * 64 + ((cc + t) & 63)];
    }
    s_out[node0 + t] = sv;
  }
}

// ---------------- K3: fused softmax stats + top-k select + single-pass pools ----------------
__global__ __launch_bounds__(512) void k_pool_fused(const float* __restrict__ x,
                                                    const float* __restrict__ s,
                                                    const int* __restrict__ seg_start,
                                                    float* __restrict__ pooled) {
  const int b = blockIdx.x;
  const int t = threadIdx.x;
  const int start = seg_start[b];
  const int end = seg_start[b + 1];
  const int n = end - start;

  __shared__ float s_lds[1024];
  __shared__ float red[512];
  __shared__ float thr_sh;
  __shared__ int thri_sh;
  __shared__ float r4[8][264];

  const bool fits = (n <= 1024);
  if (fits) {
    for (int i = t; i < n; i += 512) s_lds[i] = s[start + i];
  }
  __syncthreads();
  const float* sseg = fits ? s_lds : (s + start);

  float m = -INFINITY;
  for (int i = t; i < n; i += 512) m = fmaxf(m, sseg[i]);
  red[t] = m;
  __syncthreads();
  for (int off = 256; off > 0; off >>= 1) {
    if (t < off) red[t] = fmaxf(red[t], red[t + off]);
    __syncthreads();
  }
  const float smax = red[0];
  __syncthreads();
  float d = 0.f;
  for (int i = t; i < n; i += 512) d += __expf(sseg[i] - smax);
  red[t] = d;
  __syncthreads();
  for (int off = 256; off > 0; off >>= 1) {
    if (t < off) red[t] += red[t + off];
    __syncthreads();
  }
  const float denom = red[0];
  __syncthreads();
  const float inv_denom = (denom > 0.f) ? 1.f / denom : 0.f;

  int k = 0;
  if (n > 0) {
    k = (int)ceilf(0.05f * (float)n);
    if (k < 5) k = 5;
    if (k > 64) k = 64;
    if (k > n) k = n;
  }

  if (t < 64) {
    float pk = INFINITY;
    int pidx = -1;
    for (int r = 0; r < k; ++r) {
      float bk = -INFINITY;
      int bi = 0x7fffffff;
      for (int i = t; i < n; i += 64) {
        const float si = sseg[i];
        const int gi = start + i;
        const bool below = (si < pk) || (si == pk && gi > pidx);
        if (below && (si > bk || (si == bk && gi < bi))) { bk = si; bi = gi; }
      }
#pragma unroll
      for (int off = 32; off > 0; off >>= 1) {
        const float ok = __shfl_xor(bk, off);
        const int oi = __shfl_xor(bi, off);
        if (ok > bk || (ok == bk && oi < bi)) { bk = ok; bi = oi; }
      }
      pk = bk;
      pidx = bi;
    }
    if (t == 0) {
      thr_sh = (k > 0) ? pk : INFINITY;
      thri_sh = (k > 0) ? pidx : -1;
    }
  }
  __syncthreads();
  const float thr = thr_sh;
  const int thri = thri_sh;

  const int fq = t & 63;
  const int sub = t >> 6;
  float mean[4] = {0.f, 0.f, 0.f, 0.f};
  float attn[4] = {0.f, 0.f, 0.f, 0.f};
  float tk[4] = {0.f, 0.f, 0.f, 0.f};
  float mx[4] = {-INFINITY, -INFINITY, -INFINITY, -INFINITY};
  for (int i = sub; i < n; i += 8) {
    const float si = sseg[i];
    const float wi = __expf(si - smax);
    const int gi = start + i;
    const bool sel = (si > thr) || (si == thr && gi <= thri);
    const float4 xv = *reinterpret_cast<const float4*>(x + (size_t)gi * H + fq * 4);
    mean[0] += xv.x; mean[1] += xv.y; mean[2] += xv.z; mean[3] += xv.w;
    attn[0] = fmaf(xv.x, wi, attn[0]);
    attn[1] = fmaf(xv.y, wi, attn[1]);
    attn[2] = fmaf(xv.z, wi, attn[2]);
    attn[3] = fmaf(xv.w, wi, attn[3]);
    mx[0] = fmaxf(mx[0], xv.x);
    mx[1] = fmaxf(mx[1], xv.y);
    mx[2] = fmaxf(mx[2], xv.z);
    mx[3] = fmaxf(mx[3], xv.w);
    if (sel) {
      tk[0] += xv.x; tk[1] += xv.y; tk[2] += xv.z; tk[3] += xv.w;
    }
  }
  float* po = pooled + (size_t)b * 1024;
  const float invn = 1.f / (float)(n > 0 ? n : 1);
  const float invk = (k > 0) ? 1.f / (float)k : 0.f;
  *reinterpret_cast<float4*>(&r4[sub][fq * 4]) = make_float4(mean[0], mean[1], mean[2], mean[3]);
  __syncthreads();
  if (t < 256) {
    float tot = 0.f;
#pragma unroll
    for (int q = 0; q < 8; ++q) tot += r4[q][t];
    po[t] = tot * invn;
  }
  __syncthreads();
  *reinterpret_cast<float4*>(&r4[sub][fq * 4]) = make_float4(attn[0], attn[1], attn[2], attn[3]);
  __syncthreads();
  if (t < 256) {
    float tot = 0.f;
#pragma unroll
    for (int q = 0; q < 8; ++q) tot += r4[q][t];
    po[256 + t] = tot * inv_denom;
  }
  __syncthreads();
  *reinterpret_cast<float4*>(&r4[sub][fq * 4]) = make_float4(mx[0], mx[1], mx[2], mx[3]);
  __syncthreads();
  if (t < 256) {
    float tot = -INFINITY;
#pragma unroll
    for (int q = 0; q < 8; ++q) tot = fmaxf(tot, r4[q][t]);
    po[512 + t] = (n > 0) ? tot : 0.f;
  }
  __syncthreads();
  *reinterpret_cast<float4*>(&r4[sub][fq * 4]) = make_float4(tk[0], tk[1], tk[2], tk[3]);
  __syncthreads();
  if (t < 256) {
    float tot = 0.f;
#pragma unroll
    for (int q = 0; q < 8; ++q) tot += r4[q][t];
    po[768 + t] = tot * invk;
  }
}

// ---------------- K5: final GEMM [512,1024]@[1024,256], split-K=8 ----------------
__global__ __launch_bounds__(256) void k_gemm(const float* __restrict__ pooled,
                                              const float* __restrict__ Wf,
                                              float* __restrict__ gacc) {
  const int t = threadIdx.x;
  const int r0 = blockIdx.x * 8;
  const int kc0 = blockIdx.y * 128;
  __shared__ float ps[8][132];
  {
    const int r = t >> 5;
    const int c = (t & 31) << 2;
    *reinterpret_cast<float4*>(&ps[r][c]) =
        *reinterpret_cast<const float4*>(pooled + (size_t)(r0 + r) * 1024 + kc0 + c);
  }
  __syncthreads();
  float acc[8];
#pragma unroll
  for (int r = 0; r < 8; ++r) acc[r] = 0.f;
#pragma unroll 4
  for (int c = 0; c < 128; ++c) {
    const float wf = Wf[(size_t)(kc0 + c) * 256 + t];
#pragma unroll
    for (int r = 0; r < 8; ++r) acc[r] = fmaf(ps[r][c], wf, acc[r]);
  }
  float* go = gacc + ((size_t)blockIdx.y * B_GRAPHS + r0) * 256;
#pragma unroll
  for (int r = 0; r < 8; ++r) go[r * 256 + t] = acc[r];
}

// ---------------- K6: reduce split-K + bias + relu -> out ----------------
__global__ __launch_bounds__(256) void k_out(const float* __restrict__ gacc,
                                             const float* __restrict__ bf,
                                             float* __restrict__ out) {
  const int i = blockIdx.x * 256 + threadIdx.x;
  float v = bf[i & 255];
#pragma unroll
  for (int ks = 0; ks < 8; ++ks) v += gacc[(size_t)ks * (B_GRAPHS * 256) + i];
  out[i] = fmaxf(v, 0.f);
}

extern "C" void kernel_launch(void* const* d_in, const int* in_sizes, int n_in,
                              void* d_out, int out_size, void* d_ws, size_t ws_size,
                              hipStream_t stream) {
  const float* x  = (const float*)d_in[0];
  const int* batch = (const int*)d_in[1];
  const float* W1 = (const float*)d_in[2];
  const float* b1 = (const float*)d_in[3];
  const float* W2 = (const float*)d_in[4];
  const float* b2 = (const float*)d_in[5];
  const float* Wf = (const float*)d_in[6];
  const float* bf = (const float*)d_in[7];
  const int N = in_sizes[1];     // 131072
  const int B = B_GRAPHS;

  // ws floats: s[N] | seg_start[1024 ints] | pooled[B*1024] | gacc[8*B*256] | W1f[2*32768 u16]
  float* ws = (float*)d_ws;
  float* s = ws;
  int* seg_start = (int*)(ws + N);
  float* pooled = ws + N + 1024;
  float* gacc = pooled + (size_t)B * 1024;
  ushort* W1f = (ushort*)(gacc + (size_t)8 * B * 256);

  k_prep_w1<<<dim3(128), dim3(256), 0, stream>>>(W1, W1f);
  k_seg_bounds<<<dim3((B + 1 + 255) / 256), dim3(256), 0, stream>>>(batch, seg_start, N, B);
  k_score_mfma<<<dim3(N / 128), dim3(256), 0, stream>>>(x, W1f, b1, W2, b2, s);
  k_pool_fused<<<dim3(B), dim3(512), 0, stream>>>(x, s, seg_start, pooled);
  k_gemm<<<dim3(B / 8, 8), dim3(256), 0, stream>>>(pooled, Wf, gacc);
  k_out<<<dim3((B * 256) / 256), dim3(256), 0, stream>>>(gacc, bf, (float*)d_out);
}

// Round 8
// 110.414 us; speedup vs baseline: 1.3306x; 1.3306x over previous
//
#include <hip/hip_runtime.h>
#include <math.h>

#define H 256
#define HH 128
#define B_GRAPHS 512

typedef __attribute__((ext_vector_type(8))) short bfrag8;   // 8 bf16
typedef __attribute__((ext_vector_type(16))) float f32x16;

// ---------------- K0: pre-split W1 into 2 bf16 planes (truncate + residual),
// fragment-major: base = ((kks*2+g)*128 + col)*8 + e, k = kks*16 + g*8 + e ----------------
__global__ void k_prep_w1(const float* __restrict__ W1, ushort* __restrict__ W1b) {
  const int idx = blockIdx.x * 256 + threadIdx.x;  // 32768 = 256*128
  const int k = idx >> 7, c = idx & 127;
  const float v = W1[idx];  // W1 is [256][128] row-major
  const uint u = __builtin_bit_cast(uint, v);
  const float r = v - __builtin_bit_cast(float, u & 0xFFFF0000u);
  const int base = (((k >> 4) * 2 + ((k >> 3) & 1)) * 128 + c) * 8 + (k & 7);
  W1b[base] = (ushort)(u >> 16);
  W1b[32768 + base] = (ushort)(__builtin_bit_cast(uint, r) >> 16);
}

// ---------------- K1: segment bounds (batch is sorted) ----------------
__global__ void k_seg_bounds(const int* __restrict__ batch, int* __restrict__ seg_start,
                             int N, int B) {
  int b = blockIdx.x * blockDim.x + threadIdx.x;
  if (b > B) return;
  int lo = 0, hi = N;
  while (lo < hi) {
    int mid = (lo + hi) >> 1;
    if (batch[mid] < b) lo = mid + 1; else hi = mid;
  }
  seg_start[b] = lo;
}

// ---------------- K2: score MLP — barrier-free, wave-per-32-node-chunk streaming ----------
__device__ __forceinline__ void splitbf(const float4 v0, const float4 v1,
                                        bfrag8& a0, bfrag8& a1) {
  const float vals[8] = {v0.x, v0.y, v0.z, v0.w, v1.x, v1.y, v1.z, v1.w};
#pragma unroll
  for (int e = 0; e < 8; ++e) {
    const uint u = __builtin_bit_cast(uint, vals[e]);
    a0[e] = (short)(u >> 16);
    const float r = vals[e] - __builtin_bit_cast(float, u & 0xFFFF0000u);
    a1[e] = (short)(__builtin_bit_cast(uint, r) >> 16);
  }
}

__global__ __launch_bounds__(256, 3) void k_score_mfma(
    const float* __restrict__ x, const ushort* __restrict__ W1b,
    const float* __restrict__ b1, const float* __restrict__ W2,
    const float* __restrict__ b2, float* __restrict__ s_out) {
  __shared__ float xs[4][2192];  // per-wave slice buffer [32 rows][68 pad] (+16 slack)
  const int t = threadIdx.x;
  const int lane = t & 63;
  const int w = t >> 6;
  const int nl = lane & 31, g = lane >> 5;
  const int chunk = blockIdx.x * 4 + w;
  const int node0 = chunk * 32;
  float* myxs = &xs[w][0];

  f32x16 acc[4];
  acc[0] = (f32x16)0.f; acc[1] = (f32x16)0.f;
  acc[2] = (f32x16)0.f; acc[3] = (f32x16)0.f;

  // staging roles: lane covers row (q*4 + lrow), 16B chunk lcol of the 64-col slice
  const int lrow = lane >> 4;   // 0..3
  const int lcol = lane & 15;   // 0..15
  const float* gsrc = x + (size_t)(node0 + lrow) * H + lcol * 4;

  float4 gx[8];
#pragma unroll
  for (int q = 0; q < 8; ++q)
    gx[q] = *(const float4*)(gsrc + (size_t)(q * 4) * H);

#pragma unroll
  for (int ks = 0; ks < 4; ++ks) {
    // write slice ks into wave-private LDS (no block barrier; intra-wave lgkmcnt only)
#pragma unroll
    for (int q = 0; q < 8; ++q)
      *(float4*)&myxs[(q * 4 + lrow) * 68 + lcol * 4] = gx[q];
    // prefetch slice ks+1 (hidden under this slice's compute)
    if (ks < 3) {
#pragma unroll
      for (int q = 0; q < 8; ++q)
        gx[q] = *(const float4*)(gsrc + (size_t)(q * 4) * H + (ks + 1) * 64);
    }
    // compute: 4 substeps (K=16 each), 12 MFMA per substep
#pragma unroll
    for (int sub = 0; sub < 4; ++sub) {
      const int kks = ks * 4 + sub;
      const float4 v0 = *(const float4*)&myxs[nl * 68 + sub * 16 + g * 8];
      const float4 v1 = *(const float4*)&myxs[nl * 68 + sub * 16 + g * 8 + 4];
      bfrag8 a0, a1;
      splitbf(v0, v1, a0, a1);
#pragma unroll
      for (int j = 0; j < 4; ++j) {
        const ushort* bp = W1b + (size_t)((kks * 2 + g) * 128 + j * 32 + nl) * 8;
        const bfrag8 b0 = *(const bfrag8*)bp;
        const bfrag8 b1f = *(const bfrag8*)(bp + 32768);
        acc[j] = __builtin_amdgcn_mfma_f32_32x32x16_bf16(a0, b0, acc[j], 0, 0, 0);
        acc[j] = __builtin_amdgcn_mfma_f32_32x32x16_bf16(a0, b1f, acc[j], 0, 0, 0);
        acc[j] = __builtin_amdgcn_mfma_f32_32x32x16_bf16(a1, b0, acc[j], 0, 0, 0);
      }
    }
  }

  // ---- epilogue: layer 2 + cross-lane reduce (proven C/D map: row=(r&3)+8*(r>>2)+4g, col=nl)
  float b1v[4], w2v[4];
#pragma unroll
  for (int j = 0; j < 4; ++j) {
    b1v[j] = b1[j * 32 + nl];
    w2v[j] = W2[j * 32 + nl];
  }
  float p[16];
#pragma unroll
  for (int r = 0; r < 16; ++r) {
    float v = 0.f;
#pragma unroll
    for (int j = 0; j < 4; ++j)
      v = fmaf(fmaxf(acc[j][r] + b1v[j], 0.f), w2v[j], v);
#pragma unroll
    for (int m = 1; m <= 16; m <<= 1) v += __shfl_xor(v, m);
    p[r] = v;
  }
  if (nl == 0) {
    const float bb = b2[0];
#pragma unroll
    for (int r = 0; r < 16; ++r) {
      const int row = (r & 3) + 8 * (r >> 2) + 4 * g;
      s_out[node0 + row] = p[r] + bb;
    }
  }
}

// ---------------- K3: fused softmax stats + top-k select + single-pass pools ----------------
__global__ __launch_bounds__(512) void k_pool_fused(const float* __restrict__ x,
                                                    const float* __restrict__ s,
                                                    const int* __restrict__ seg_start,
                                                    float* __restrict__ pooled) {
  const int b = blockIdx.x;
  const int t = threadIdx.x;
  const int start = seg_start[b];
  const int end = seg_start[b + 1];
  const int n = end - start;

  __shared__ float s_lds[1024];
  __shared__ float red[512];
  __shared__ float thr_sh;
  __shared__ int thri_sh;
  __shared__ float r4[8][264];

  const bool fits = (n <= 1024);
  if (fits) {
    for (int i = t; i < n; i += 512) s_lds[i] = s[start + i];
  }
  __syncthreads();
  const float* sseg = fits ? s_lds : (s + start);

  float m = -INFINITY;
  for (int i = t; i < n; i += 512) m = fmaxf(m, sseg[i]);
  red[t] = m;
  __syncthreads();
  for (int off = 256; off > 0; off >>= 1) {
    if (t < off) red[t] = fmaxf(red[t], red[t + off]);
    __syncthreads();
  }
  const float smax = red[0];
  __syncthreads();
  float d = 0.f;
  for (int i = t; i < n; i += 512) d += __expf(sseg[i] - smax);
  red[t] = d;
  __syncthreads();
  for (int off = 256; off > 0; off >>= 1) {
    if (t < off) red[t] += red[t + off];
    __syncthreads();
  }
  const float denom = red[0];
  __syncthreads();
  const float inv_denom = (denom > 0.f) ? 1.f / denom : 0.f;

  int k = 0;
  if (n > 0) {
    k = (int)ceilf(0.05f * (float)n);
    if (k < 5) k = 5;
    if (k > 64) k = 64;
    if (k > n) k = n;
  }

  if (t < 64) {
    float pk = INFINITY;
    int pidx = -1;
    for (int r = 0; r < k; ++r) {
      float bk = -INFINITY;
      int bi = 0x7fffffff;
      for (int i = t; i < n; i += 64) {
        const float si = sseg[i];
        const int gi = start + i;
        const bool below = (si < pk) || (si == pk && gi > pidx);
        if (below && (si > bk || (si == bk && gi < bi))) { bk = si; bi = gi; }
      }
#pragma unroll
      for (int off = 32; off > 0; off >>= 1) {
        const float ok = __shfl_xor(bk, off);
        const int oi = __shfl_xor(bi, off);
        if (ok > bk || (ok == bk && oi < bi)) { bk = ok; bi = oi; }
      }
      pk = bk;
      pidx = bi;
    }
    if (t == 0) {
      thr_sh = (k > 0) ? pk : INFINITY;
      thri_sh = (k > 0) ? pidx : -1;
    }
  }
  __syncthreads();
  const float thr = thr_sh;
  const int thri = thri_sh;

  const int fq = t & 63;
  const int sub = t >> 6;
  float mean[4] = {0.f, 0.f, 0.f, 0.f};
  float attn[4] = {0.f, 0.f, 0.f, 0.f};
  float tk[4] = {0.f, 0.f, 0.f, 0.f};
  float mx[4] = {-INFINITY, -INFINITY, -INFINITY, -INFINITY};
  for (int i = sub; i < n; i += 8) {
    const float si = sseg[i];
    const float wi = __expf(si - smax);
    const int gi = start + i;
    const bool sel = (si > thr) || (si == thr && gi <= thri);
    const float4 xv = *reinterpret_cast<const float4*>(x + (size_t)gi * H + fq * 4);
    mean[0] += xv.x; mean[1] += xv.y; mean[2] += xv.z; mean[3] += xv.w;
    attn[0] = fmaf(xv.x, wi, attn[0]);
    attn[1] = fmaf(xv.y, wi, attn[1]);
    attn[2] = fmaf(xv.z, wi, attn[2]);
    attn[3] = fmaf(xv.w, wi, attn[3]);
    mx[0] = fmaxf(mx[0], xv.x);
    mx[1] = fmaxf(mx[1], xv.y);
    mx[2] = fmaxf(mx[2], xv.z);
    mx[3] = fmaxf(mx[3], xv.w);
    if (sel) {
      tk[0] += xv.x; tk[1] += xv.y; tk[2] += xv.z; tk[3] += xv.w;
    }
  }
  float* po = pooled + (size_t)b * 1024;
  const float invn = 1.f / (float)(n > 0 ? n : 1);
  const float invk = (k > 0) ? 1.f / (float)k : 0.f;
  *reinterpret_cast<float4*>(&r4[sub][fq * 4]) = make_float4(mean[0], mean[1], mean[2], mean[3]);
  __syncthreads();
  if (t < 256) {
    float tot = 0.f;
#pragma unroll
    for (int q = 0; q < 8; ++q) tot += r4[q][t];
    po[t] = tot * invn;
  }
  __syncthreads();
  *reinterpret_cast<float4*>(&r4[sub][fq * 4]) = make_float4(attn[0], attn[1], attn[2], attn[3]);
  __syncthreads();
  if (t < 256) {
    float tot = 0.f;
#pragma unroll
    for (int q = 0; q < 8; ++q) tot += r4[q][t];
    po[256 + t] = tot * inv_denom;
  }
  __syncthreads();
  *reinterpret_cast<float4*>(&r4[sub][fq * 4]) = make_float4(mx[0], mx[1], mx[2], mx[3]);
  __syncthreads();
  if (t < 256) {
    float tot = -INFINITY;
#pragma unroll
    for (int q = 0; q < 8; ++q) tot = fmaxf(tot, r4[q][t]);
    po[512 + t] = (n > 0) ? tot : 0.f;
  }
  __syncthreads();
  *reinterpret_cast<float4*>(&r4[sub][fq * 4]) = make_float4(tk[0], tk[1], tk[2], tk[3]);
  __syncthreads();
  if (t < 256) {
    float tot = 0.f;
#pragma unroll
    for (int q = 0; q < 8; ++q) tot += r4[q][t];
    po[768 + t] = tot * invk;
  }
}

// ---------------- K5: final GEMM [512,1024]@[1024,256], split-K=8 ----------------
__global__ __launch_bounds__(256) void k_gemm(const float* __restrict__ pooled,
                                              const float* __restrict__ Wf,
                                              float* __restrict__ gacc) {
  const int t = threadIdx.x;
  const int r0 = blockIdx.x * 8;
  const int kc0 = blockIdx.y * 128;
  __shared__ float ps[8][132];
  {
    const int r = t >> 5;
    const int c = (t & 31) << 2;
    *reinterpret_cast<float4*>(&ps[r][c]) =
        *reinterpret_cast<const float4*>(pooled + (size_t)(r0 + r) * 1024 + kc0 + c);
  }
  __syncthreads();
  float acc[8];
#pragma unroll
  for (int r = 0; r < 8; ++r) acc[r] = 0.f;
#pragma unroll 4
  for (int c = 0; c < 128; ++c) {
    const float wf = Wf[(size_t)(kc0 + c) * 256 + t];
#pragma unroll
    for (int r = 0; r < 8; ++r) acc[r] = fmaf(ps[r][c], wf, acc[r]);
  }
  float* go = gacc + ((size_t)blockIdx.y * B_GRAPHS + r0) * 256;
#pragma unroll
  for (int r = 0; r < 8; ++r) go[r * 256 + t] = acc[r];
}

// ---------------- K6: reduce split-K + bias + relu -> out ----------------
__global__ __launch_bounds__(256) void k_out(const float* __restrict__ gacc,
                                             const float* __restrict__ bf,
                                             float* __restrict__ out) {
  const int i = blockIdx.x * 256 + threadIdx.x;
  float v = bf[i & 255];
#pragma unroll
  for (int ks = 0; ks < 8; ++ks) v += gacc[(size_t)ks * (B_GRAPHS * 256) + i];
  out[i] = fmaxf(v, 0.f);
}

extern "C" void kernel_launch(void* const* d_in, const int* in_sizes, int n_in,
                              void* d_out, int out_size, void* d_ws, size_t ws_size,
                              hipStream_t stream) {
  const float* x  = (const float*)d_in[0];
  const int* batch = (const int*)d_in[1];
  const float* W1 = (const float*)d_in[2];
  const float* b1 = (const float*)d_in[3];
  const float* W2 = (const float*)d_in[4];
  const float* b2 = (const float*)d_in[5];
  const float* Wf = (const float*)d_in[6];
  const float* bf = (const float*)d_in[7];
  const int N = in_sizes[1];     // 131072
  const int B = B_GRAPHS;

  // ws floats: s[N] | seg_start[1024 ints] | pooled[B*1024] | gacc[8*B*256] | W1b[2*32768 u16]
  float* ws = (float*)d_ws;
  float* s = ws;
  int* seg_start = (int*)(ws + N);
  float* pooled = ws + N + 1024;
  float* gacc = pooled + (size_t)B * 1024;
  ushort* W1b = (ushort*)(gacc + (size_t)8 * B * 256);

  k_prep_w1<<<dim3(128), dim3(256), 0, stream>>>(W1, W1b);
  k_seg_bounds<<<dim3((B + 1 + 255) / 256), dim3(256), 0, stream>>>(batch, seg_start, N, B);
  k_score_mfma<<<dim3(N / 128), dim3(256), 0, stream>>>(x, W1b, b1, W2, b2, s);
  k_pool_fused<<<dim3(B), dim3(512), 0, stream>>>(x, s, seg_start, pooled);
  k_gemm<<<dim3(B / 8, 8), dim3(256), 0, stream>>>(pooled, Wf, gacc);
  k_out<<<dim3((B * 256) / 256), dim3(256), 0, stream>>>(gacc, bf, (float*)d_out);
}